// Round 18
// baseline (837.314 us; speedup 1.0000x reference)
//
#include <hip/hip_runtime.h>
#include <stdint.h>

#define DEVI static __device__ __forceinline__

typedef __attribute__((ext_vector_type(8))) _Float16  f16x8;
typedef __attribute__((ext_vector_type(8))) uint16_t  u16x8;
typedef __attribute__((ext_vector_type(4))) uint16_t  u16x4;
typedef __attribute__((ext_vector_type(4))) float     f32x4;

DEVI uint16_t f2h(float f){ return __builtin_bit_cast(uint16_t, (_Float16)f); }

DEVI void gload_lds16(const void* g, void* l){
  __builtin_amdgcn_global_load_lds((__attribute__((address_space(1))) void*)g,
                                   (__attribute__((address_space(3))) void*)l, 16, 0, 0);
}
DEVI f16x8 frag_ld(const void* base, int byteoff){
  const u16x8* p = (const u16x8*)((const char*)base + byteoff);
  return __builtin_bit_cast(f16x8, *p);
}

// ---------------------------------------------------------------- prep_all
// ONE launch for all weight transposes + embedding (R16: -18us vs 8 launches).
__global__ __launch_bounds__(256) void prep_all(
    const float* __restrict__ Wq, const float* __restrict__ Wk,
    const float* __restrict__ Wv, const float* __restrict__ Wproj,
    const float* __restrict__ W1, const float* __restrict__ W2,
    const float* __restrict__ Wlm,
    const int* __restrict__ idx, const float* __restrict__ tok,
    const float* __restrict__ pos,
    uint16_t* __restrict__ qkvT, uint16_t* __restrict__ WprojT,
    uint16_t* __restrict__ W1T, uint16_t* __restrict__ W2T,
    uint16_t* __restrict__ WlmT, float* __restrict__ xf,
    uint16_t* __restrict__ xb)
{
  __shared__ float tile[64][65];
  const int id = blockIdx.x;
  const float* inp; uint16_t* outp;
  int ld_in, ld_out, r0, c0;

  if (id < 3072){                       // Wq/Wk/Wv: 3 x 1024 tiles
    const int which = id >> 10, t = id & 1023;
    const int x = t >> 6, z = t & 63;   // x: 16 row-tiles of D; z = l*16+h
    const float* W = (which == 0) ? Wq : (which == 1) ? Wk : Wv;
    inp  = W + (long long)z * 65536;
    outp = qkvT + (size_t)(z >> 4) * (3072 * 1024)
                + (size_t)(z & 15) * (64 * 1024)
                + (size_t)which * (1024 * 1024);
    ld_in = 64; ld_out = 1024; r0 = x * 64; c0 = 0;
  } else if (id < 4096){                // Wproj: 1024 tiles (x16,y16,z4)
    const int t = id - 3072;
    const int z = t & 3, y = (t >> 2) & 15, x = t >> 6;
    inp  = Wproj + (long long)z * 1048576;
    outp = WprojT + (size_t)z * 1048576;
    ld_in = 1024; ld_out = 1024; r0 = x * 64; c0 = y * 64;
  } else if (id < 8192){                // W1: 4096 tiles (x16,y64,z4)
    const int t = id - 4096;
    const int z = t & 3, y = (t >> 2) & 63, x = t >> 8;
    inp  = W1 + (long long)z * 4194304;
    outp = W1T + (size_t)z * 4194304;
    ld_in = 4096; ld_out = 1024; r0 = x * 64; c0 = y * 64;
  } else if (id < 12288){               // W2: 4096 tiles (x64,y16,z4)
    const int t = id - 8192;
    const int z = t & 3, y = (t >> 2) & 15, x = t >> 6;
    inp  = W2 + (long long)z * 4194304;
    outp = W2T + (size_t)z * 4194304;
    ld_in = 1024; ld_out = 4096; r0 = x * 64; c0 = y * 64;
  } else if (id < 20288){               // Wlm: 8000 tiles (x16,y500)
    const int t = id - 12288;
    const int x = t & 15, y = t >> 4;
    inp = Wlm; outp = WlmT;
    ld_in = 32000; ld_out = 1024; r0 = x * 64; c0 = y * 64;
  } else {                              // embed: 2048 blocks (b*T + t)
    const int t = id - 20288;
    const int d = threadIdx.x * 4;
    const int token = idx[t];
    const int tp = t & 1023;
    const float4 tv = *(const float4*)(tok + (size_t)token * 1024 + d);
    const float4 pv = *(const float4*)(pos + (size_t)tp * 1024 + d);
    float4 s; s.x = tv.x + pv.x; s.y = tv.y + pv.y; s.z = tv.z + pv.z; s.w = tv.w + pv.w;
    *(float4*)(xf + (size_t)t * 1024 + d) = s;
    uint16_t* o = xb + (size_t)t * 1024 + d;
    o[0] = f2h(s.x); o[1] = f2h(s.y); o[2] = f2h(s.z); o[3] = f2h(s.w);
    return;
  }

  // shared 64x64 transpose body (float4 reads, paired-row u32 writes)
  const int r16 = threadIdx.x >> 4, c4 = (threadIdx.x & 15) * 4;
  #pragma unroll
  for (int i = 0; i < 4; i++){
    int r = i * 16 + r16;
    const float4 v = *(const float4*)(inp + (long long)(r0 + r) * ld_in + (c0 + c4));
    tile[r][c4] = v.x; tile[r][c4 + 1] = v.y; tile[r][c4 + 2] = v.z; tile[r][c4 + 3] = v.w;
  }
  __syncthreads();
  const int rp = (threadIdx.x & 31) * 2;
  const int cy = threadIdx.x >> 5;
  #pragma unroll
  for (int i = 0; i < 8; i++){
    int c = i * 8 + cy;
    uint32_t v = (uint32_t)f2h(tile[rp][c]) | ((uint32_t)f2h(tile[rp + 1][c]) << 16);
    *(uint32_t*)(outp + (long long)(c0 + c) * ld_out + (r0 + rp)) = v;
  }
}

// ---------------------------------------------------------------- GEMM
// C(MxN) = A(MxK fp16, row-major) * Bt(NxK fp16)^T  [+bias] [+res] [relu]
// 128x128 tile, BK=64, 4 waves (2x2), mfma 16x16x32 f16, global_load_lds w16,
// XOR-swizzled LDS via pre-swizzled global source. XCD-chunked swizzle.
// launch_bounds(256,3): unified VGPR+AGPR = 132; occ-4 cap squeezed (R11).
// SK4: 4-way split-K (R17: -55us on FFN2 — 1/CU runs at half pace).
// QSCALE folds D^-0.5 * log2(e) into Q so attn uses exp2 directly.
template<bool SPLITK, bool SK4, bool BIAS, bool RELU, bool RES, bool OUTF, bool OUTB, bool QSCALE>
__global__ __launch_bounds__(256, 3) void gemm_bt(
    const uint16_t* __restrict__ A, const uint16_t* __restrict__ Bt,
    const float* __restrict__ bias, const float* __restrict__ res,
    float* __restrict__ outf, float* __restrict__ outf2,
    uint16_t* __restrict__ outb,
    int M, int N, int K)
{
  __shared__ __align__(16) uint16_t As[128 * 64];
  __shared__ __align__(16) uint16_t Bs[128 * 64];
  const int tid = threadIdx.x, lane = tid & 63, wid = tid >> 6;

  const int Mt = M >> 7;
  int flat = blockIdx.x;
  int kidx = 0;
  if constexpr (SK4){ kidx = flat & 3; flat >>= 2; }
  else if constexpr (SPLITK){ kidx = flat & 1; flat >>= 1; }
  const int total = SK4 ? (gridDim.x >> 2) : (SPLITK ? (gridDim.x >> 1) : gridDim.x);
  const int wg = (flat & 7) * (total >> 3) + (flat >> 3);   // XCD-chunked, total%8==0
  const int bm = (wg % Mt) * 128, bn = (wg / Mt) * 128;
  int k0 = 0, k1 = K;
  if constexpr (SK4){ const int Kq = K >> 2; k0 = kidx * Kq; k1 = k0 + Kq; }
  else if constexpr (SPLITK){ const int Kh = K >> 1; k0 = kidx * Kh; k1 = k0 + Kh; }
  float* outp = outf;
  if constexpr (SK4) outp = ((kidx < 2) ? outf : outf2) + (size_t)(kidx & 1) * M * N;
  else if constexpr (SPLITK) outp = outf + (size_t)kidx * M * N;

  const uint16_t* gA[4]; const uint16_t* gB[4];
  #pragma unroll
  for (int i = 0; i < 4; i++){
    int c = i * 256 + tid;
    int row = c >> 3;
    int p = (c * 16) ^ ((row & 7) << 4);   // logical byte this LDS slot holds
    int off = (p >> 1) & 63;               // k-element within row
    gA[i] = A  + (size_t)(bm + row) * K + off;
    gB[i] = Bt + (size_t)(bn + row) * K + off;
  }

  f32x4 acc[4][4];
  const f32x4 fz = {0.f, 0.f, 0.f, 0.f};
  #pragma unroll
  for (int a = 0; a < 4; a++)
    #pragma unroll
    for (int n = 0; n < 4; n++) acc[a][n] = fz;

  const int lrow = lane & 15, lk2 = (lane >> 4) * 16;
  const int wr = (wid >> 1) * 64, wc = (wid & 1) * 64;

  for (int kt = k0; kt < k1; kt += 64){
    #pragma unroll
    for (int i = 0; i < 4; i++)
      gload_lds16(gA[i] + kt, (char*)As + (i * 256 + wid * 64) * 16);
    #pragma unroll
    for (int i = 0; i < 4; i++)
      gload_lds16(gB[i] + kt, (char*)Bs + (i * 256 + wid * 64) * 16);
    __syncthreads();
    #pragma unroll
    for (int kk = 0; kk < 2; kk++){
      f16x8 af[4], bfv[4];
      #pragma unroll
      for (int mf = 0; mf < 4; mf++){
        int row = wr + mf * 16 + lrow;
        af[mf] = frag_ld(As, (row * 128 + kk * 64 + lk2) ^ ((row & 7) << 4));
      }
      #pragma unroll
      for (int nf = 0; nf < 4; nf++){
        int row = wc + nf * 16 + lrow;
        bfv[nf] = frag_ld(Bs, (row * 128 + kk * 64 + lk2) ^ ((row & 7) << 4));
      }
      #pragma unroll
      for (int mf = 0; mf < 4; mf++)
        #pragma unroll
        for (int nf = 0; nf < 4; nf++)
          acc[mf][nf] = __builtin_amdgcn_mfma_f32_16x16x32_f16(af[mf], bfv[nf], acc[mf][nf], 0, 0, 0);
    }
    __syncthreads();
  }

  #pragma unroll
  for (int mf = 0; mf < 4; mf++){
    const int row0 = bm + wr + mf * 16 + (lane >> 4) * 4;
    #pragma unroll
    for (int nf = 0; nf < 4; nf++){
      const int col = bn + wc + nf * 16 + (lane & 15);
      float bv = 0.f;
      if constexpr (BIAS) bv = bias[col];
      float qs = 1.0f;
      if constexpr (QSCALE) qs = (col < 1024) ? 0.04508422f : 1.0f;  // log2(e)/32
      #pragma unroll
      for (int j = 0; j < 4; j++){
        float v = acc[mf][nf][j] + bv;
        size_t oi = (size_t)(row0 + j) * N + col;
        if constexpr (RES)  v += res[oi];
        if constexpr (RELU) v = fmaxf(v, 0.f);
        if constexpr (OUTF) outp[oi] = v;
        if constexpr (OUTB) outb[oi] = f2h(v * qs);
      }
    }
  }
}

// ------------------------------------------------------- LM-head GEMM
// 128x256 tile, BK=64, 512 threads / 8 waves (2Mx4N, each 64x64; acc 64
// VGPR). Proven single-buffer 2-barrier loop (R15: structure-bound).
// NEW (R18): epilogue LDS-bounce — each wave round-trips its 64x64 f32
// tile through a wave-private 4KB slice of Bs (dead post-loop; last loop
// __syncthreads already passed; intra-wave DS ordering compiler-managed)
// so stores are full 256B rows (64 lanes x consecutive f32) instead of
// 64B segments. WRITE is 256MB — the dominant LM memory cost.
__global__ __launch_bounds__(512, 1) void gemm_lm(
    const uint16_t* __restrict__ A, const uint16_t* __restrict__ Bt,
    const float* __restrict__ bias, float* __restrict__ outf,
    int M, int N, int K)
{
  __shared__ __align__(16) uint16_t As[128 * 64];
  __shared__ __align__(16) uint16_t Bs[256 * 64];
  const int tid = threadIdx.x, lane = tid & 63, wid = tid >> 6;

  const int Mt = M >> 7;                       // 16
  const int flat = blockIdx.x;
  const int wg = (flat & 7) * (gridDim.x >> 3) + (flat >> 3);
  const int bm = (wg % Mt) * 128, bn = (wg / Mt) * 256;

  const uint16_t* gA[2]; const uint16_t* gB[4];
  #pragma unroll
  for (int i = 0; i < 2; i++){
    int c = i * 512 + tid;
    int row = c >> 3;
    int p = (c * 16) ^ ((row & 7) << 4);
    int off = (p >> 1) & 63;
    gA[i] = A + (size_t)(bm + row) * K + off;
  }
  #pragma unroll
  for (int i = 0; i < 4; i++){
    int c = i * 512 + tid;
    int row = c >> 3;
    int p = (c * 16) ^ ((row & 7) << 4);
    int off = (p >> 1) & 63;
    gB[i] = Bt + (size_t)(bn + row) * K + off;
  }

  f32x4 acc[4][4];
  const f32x4 fz = {0.f, 0.f, 0.f, 0.f};
  #pragma unroll
  for (int a = 0; a < 4; a++)
    #pragma unroll
    for (int n = 0; n < 4; n++) acc[a][n] = fz;

  const int lrow = lane & 15, lk2 = (lane >> 4) * 16, g4 = (lane >> 4) * 4;
  const int wr = (wid >> 2) * 64, wc = (wid & 3) * 64;

  for (int kt = 0; kt < K; kt += 64){
    #pragma unroll
    for (int i = 0; i < 2; i++)
      gload_lds16(gA[i] + kt, (char*)As + (i * 512 + wid * 64) * 16);
    #pragma unroll
    for (int i = 0; i < 4; i++)
      gload_lds16(gB[i] + kt, (char*)Bs + (i * 512 + wid * 64) * 16);
    __syncthreads();
    #pragma unroll
    for (int kk = 0; kk < 2; kk++){
      f16x8 af[4], bfv[4];
      #pragma unroll
      for (int mf = 0; mf < 4; mf++){
        int row = wr + mf * 16 + lrow;
        af[mf] = frag_ld(As, (row * 128 + kk * 64 + lk2) ^ ((row & 7) << 4));
      }
      #pragma unroll
      for (int nf = 0; nf < 4; nf++){
        int row = wc + nf * 16 + lrow;
        bfv[nf] = frag_ld(Bs, (row * 128 + kk * 64 + lk2) ^ ((row & 7) << 4));
      }
      #pragma unroll
      for (int mf = 0; mf < 4; mf++)
        #pragma unroll
        for (int nf = 0; nf < 4; nf++)
          acc[mf][nf] = __builtin_amdgcn_mfma_f32_16x16x32_f16(af[mf], bfv[nf], acc[mf][nf], 0, 0, 0);
    }
    __syncthreads();
  }

  // epilogue: per-wave LDS-bounce transpose -> 256B coalesced stores
  float* lds_f = (float*)((char*)Bs + wid * 4096);   // wave-private 4KB
  const float bv = bias[bn + wc + lane];
  #pragma unroll
  for (int mf = 0; mf < 4; mf++){
    #pragma unroll
    for (int nf = 0; nf < 4; nf++)
      #pragma unroll
      for (int j = 0; j < 4; j++)
        lds_f[(g4 + j) * 64 + nf * 16 + lrow] = acc[mf][nf][j];
    #pragma unroll
    for (int r = 0; r < 16; r++){
      const float v = lds_f[r * 64 + lane] + bv;
      outf[(size_t)(bm + wr + mf * 16 + r) * N + (bn + wc + lane)] = v;
    }
  }
}

// 4-way split-K finish: xf += (p0+p1)+(p2+p3) + bias;  xb = fp16(xf)
__global__ __launch_bounds__(256) void reduce_sk4(
    const float* __restrict__ p, const float* __restrict__ p2,
    const float* __restrict__ bias,
    float* __restrict__ xf, uint16_t* __restrict__ xb, int MN, int N)
{
  const int i = (blockIdx.x * 256 + threadIdx.x) * 4;
  const float4 a0 = *(const float4*)(p + i);
  const float4 a1 = *(const float4*)(p + MN + i);
  const float4 a2 = *(const float4*)(p2 + i);
  const float4 a3 = *(const float4*)(p2 + MN + i);
  const int col = i & (N - 1);
  const float4 bv = *(const float4*)(bias + col);
  float4 x = *(float4*)(xf + i);
  x.x += (a0.x + a1.x) + (a2.x + a3.x) + bv.x;
  x.y += (a0.y + a1.y) + (a2.y + a3.y) + bv.y;
  x.z += (a0.z + a1.z) + (a2.z + a3.z) + bv.z;
  x.w += (a0.w + a1.w) + (a2.w + a3.w) + bv.w;
  *(float4*)(xf + i) = x;
  uint16_t* o = xb + i;
  o[0] = f2h(x.x); o[1] = f2h(x.y); o[2] = f2h(x.z); o[3] = f2h(x.w);
}

// ---------------------------------------------------------------- attention
// R9 base: launch_bounds(256,2), separate Qs, 56KB LDS, 512 balanced blocks.
// NO-MAX softmax; Q pre-scaled by D^-0.5*log2(e) in qkv epilogue so
// P = exp2(S) directly (saves 32 v_mul/lane/iter; values identical).
// Per-lane partial l, reduced once at end. 2 barriers/iter (Ps wave-private).
__global__ __launch_bounds__(256, 2) void attn_kernel(
    const uint16_t* __restrict__ qkv, uint16_t* __restrict__ out)
{
  const int bi = blockIdx.x;
  const int b  = bi >> 8;
  const int jj = bi & 255;
  const int h  = jj >> 4;
  int q64 = jj & 15;
  if (b) q64 = 15 - q64;

  __shared__ __align__(16) uint16_t Qs[64 * 64];
  __shared__ __align__(16) uint16_t Ks[128 * 64];
  __shared__ __align__(16) uint16_t Vt[64 * 128];   // V^T
  __shared__ __align__(16) uint16_t Ps[64 * 128];

  const int tid = threadIdx.x, lane = tid & 63, wid = tid >> 6;
  const size_t bt0 = (size_t)b * 1024;

  // staging map (16B granules, row-XOR-swizzle for 128B rows)
  int rowC[4], offC[4];
  #pragma unroll
  for (int i = 0; i < 4; i++){
    int c = i * 256 + tid;
    int row = c >> 3;
    int p = (c * 16) ^ ((row & 7) << 4);
    rowC[i] = row; offC[i] = (p >> 1) & 63;
  }

  // stage Q (rows q64*64 .. +64)
  #pragma unroll
  for (int i = 0; i < 2; i++)
    gload_lds16(qkv + (bt0 + q64 * 64 + rowC[i]) * 3072 + h * 64 + offC[i],
                (char*)Qs + (i * 256 + wid * 64) * 16);
  __syncthreads();

  const int lrow = lane & 15, lk2 = (lane >> 4) * 16, g4 = (lane >> 4) * 4;

  // hoist Q fragments to registers
  f16x8 aq[2];
  {
    int row = wid * 16 + lrow;
    #pragma unroll
    for (int kk = 0; kk < 2; kk++)
      aq[kk] = frag_ld(Qs, (row * 128 + kk * 64 + lk2) ^ ((row & 7) << 4));
  }

  float l_run[4];
  f32x4 acc_o[4];
  const f32x4 fz = {0.f, 0.f, 0.f, 0.f};
  #pragma unroll
  for (int j = 0; j < 4; j++){ l_run[j] = 0.f; acc_o[j] = fz; }

  const int tpV = (tid >> 3) * 2, d0V = (tid & 7) * 8;
  const int nkt = q64 >> 1;

  for (int kt = 0; kt <= nkt; ++kt){
    __syncthreads();   // prev iter LDS reads done before restage
    #pragma unroll
    for (int i = 0; i < 4; i++)
      gload_lds16(qkv + (bt0 + kt * 128 + rowC[i]) * 3072 + 1024 + h * 64 + offC[i],
                  (char*)Ks + (i * 256 + wid * 64) * 16);
    // V -> V^T: 2 iters, 2 rows x 8 cols per thread (u16x8 loads, u32 writes)
    #pragma unroll
    for (int i = 0; i < 2; i++){
      const int t = i * 64 + tpV;
      const uint16_t* src = qkv + (bt0 + kt * 128 + t) * 3072 + 2048 + h * 64 + d0V;
      const u16x8 v0 = *(const u16x8*)src;
      const u16x8 v1 = *(const u16x8*)(src + 3072);
      #pragma unroll
      for (int dd = 0; dd < 8; dd++){
        const int d = d0V + dd;
        const int byte = (d * 256 + t * 2) ^ ((((d >> 3) ^ d) & 15) << 4);
        *(uint32_t*)((char*)Vt + byte) = (uint32_t)v0[dd] | ((uint32_t)v1[dd] << 16);
      }
    }
    __syncthreads();

    // S = Q K^T  (rows wid*16..+16, 128 cols)
    f32x4 sf[8];
    #pragma unroll
    for (int n = 0; n < 8; n++) sf[n] = fz;
    __builtin_amdgcn_s_setprio(1);
    #pragma unroll
    for (int kk = 0; kk < 2; kk++){
      #pragma unroll
      for (int nf = 0; nf < 8; nf++){
        const int row = nf * 16 + lrow;
        const f16x8 bk = frag_ld(Ks, (row * 128 + kk * 64 + lk2) ^ ((row & 7) << 4));
        sf[nf] = __builtin_amdgcn_mfma_f32_16x16x32_f16(aq[kk], bk, sf[nf], 0, 0, 0);
      }
    }
    __builtin_amdgcn_s_setprio(0);

    // no-max softmax via exp2 (Q pre-scaled by log2e); masked = 0 (diag only)
    const bool diag = (kt == nkt);
    #pragma unroll
    for (int j = 0; j < 4; j++){
      float ps = 0.f;
      if (diag){
        const int rg = q64 * 64 + wid * 16 + g4 + j;
        #pragma unroll
        for (int nf = 0; nf < 8; nf++){
          const int cg = kt * 128 + nf * 16 + lrow;
          const float p = (cg <= rg) ? exp2f(sf[nf][j]) : 0.f;
          sf[nf][j] = p;
          ps += p;
        }
      } else {
        #pragma unroll
        for (int nf = 0; nf < 8; nf++){
          const float p = exp2f(sf[nf][j]);
          sf[nf][j] = p;
          ps += p;
        }
      }
      l_run[j] += ps;
      const int rl = wid * 16 + g4 + j;
      const int sw = (((rl >> 3) ^ rl) & 15) << 4;
      #pragma unroll
      for (int nf = 0; nf < 8; nf++){
        const int byte = (rl * 256 + (nf * 16 + lrow) * 2) ^ sw;
        *(uint16_t*)((char*)Ps + byte) = f2h(sf[nf][j]);
      }
    }
    // no barrier: Ps rows are wave-private (write+read same 16-row band)

    // O += P V
    __builtin_amdgcn_s_setprio(1);
    #pragma unroll
    for (int kk = 0; kk < 4; kk++){
      const int row = wid * 16 + lrow;
      const f16x8 pa = frag_ld(Ps, (row * 256 + kk * 64 + lk2) ^ ((((row >> 3) ^ row) & 15) << 4));
      #pragma unroll
      for (int nh = 0; nh < 4; nh++){
        const int n = nh * 16 + lrow;
        const f16x8 vb = frag_ld(Vt, (n * 256 + kk * 64 + lk2) ^ ((((n >> 3) ^ n) & 15) << 4));
        acc_o[nh] = __builtin_amdgcn_mfma_f32_16x16x32_f16(pa, vb, acc_o[nh], 0, 0, 0);
      }
    }
    __builtin_amdgcn_s_setprio(0);
  }

  // deferred 16-lane l reduction (once, not per tile)
  #pragma unroll
  for (int j = 0; j < 4; j++){
    #pragma unroll
    for (int mk = 1; mk < 16; mk <<= 1) l_run[j] += __shfl_xor(l_run[j], mk);
  }

  #pragma unroll
  for (int j = 0; j < 4; j++){
    const float inv = 1.f / l_run[j];
    const int rg = q64 * 64 + wid * 16 + g4 + j;
    #pragma unroll
    for (int nh = 0; nh < 4; nh++)
      out[(bt0 + rg) * 1024 + h * 64 + nh * 16 + lrow] = f2h(acc_o[nh][j] * inv);
  }
}

// ---------------------------------------------------------------- launch
extern "C" void kernel_launch(void* const* d_in, const int* in_sizes, int n_in,
                              void* d_out, int out_size, void* d_ws, size_t ws_size,
                              hipStream_t stream)
{
  const int*   idx   = (const int*)  d_in[0];
  const float* tok   = (const float*)d_in[1];
  const float* pos   = (const float*)d_in[2];
  const float* Wq    = (const float*)d_in[3];
  const float* Wk    = (const float*)d_in[4];
  const float* Wv    = (const float*)d_in[5];
  const float* Wproj = (const float*)d_in[6];
  const float* bproj = (const float*)d_in[7];
  const float* W1    = (const float*)d_in[8];
  const float* b1    = (const float*)d_in[9];
  const float* W2    = (const float*)d_in[10];
  const float* b2    = (const float*)d_in[11];
  const float* Wlm   = (const float*)d_in[12];
  const float* blm   = (const float*)d_in[13];
  float* out = (float*)d_out;

  char* ws = (char*)d_ws;
  size_t off = 0;
  auto alloc = [&](size_t bytes){ void* p = ws + off; off += (bytes + 255) & ~(size_t)255; return p; };
  uint16_t* qkvT   = (uint16_t*)alloc((size_t)4 * 3072 * 1024 * 2);
  uint16_t* WprojT = (uint16_t*)alloc((size_t)4 * 1024 * 1024 * 2);
  uint16_t* W1T    = (uint16_t*)alloc((size_t)4 * 4096 * 1024 * 2);
  uint16_t* W2T    = (uint16_t*)alloc((size_t)4 * 1024 * 4096 * 2);
  uint16_t* WlmT   = (uint16_t*)alloc((size_t)32000 * 1024 * 2);
  float*    xf     = (float*)   alloc((size_t)2048 * 1024 * 4);
  uint16_t* xb     = (uint16_t*)alloc((size_t)2048 * 1024 * 2);
  uint16_t* qkv_a  = (uint16_t*)alloc((size_t)2048 * 3072 * 2);
  uint16_t* attnb  = (uint16_t*)alloc((size_t)2048 * 1024 * 2);
  uint16_t* hb     = (uint16_t*)alloc((size_t)2048 * 4096 * 2);
  float*    psum   = (float*)   alloc((size_t)2 * 2048 * 1024 * 4);
  // psum slices 2,3 alias the DEAD qkv_a+attnb region during FFN2 (16.78MB
  // = exactly 2 x MN x 4B contiguous; both consumed before FFN2).
  float*    psum2  = (float*)qkv_a;
  (void)ws_size; (void)in_sizes; (void)n_in; (void)out_size;

  const dim3 tb(256);
  const int MN = 2048 * 1024;

  // ---- ALL weight prep + embedding in ONE launch (22336 blocks)
  prep_all<<<dim3(22336), tb, 0, stream>>>(
      Wq, Wk, Wv, Wproj, W1, W2, Wlm, idx, tok, pos,
      qkvT, WprojT, W1T, W2T, WlmT, xf, xb);

  // ---- layers
  for (int l = 0; l < 4; ++l){
    const uint16_t* qkvT_l = qkvT + (size_t)l * 3072 * 1024;
    // qkv = x @ [Wq|Wk|Wv]  (fp16 out; Q pre-scaled by log2e/32)
    gemm_bt<false, false, false, false, false, false, true, true><<<dim3(384), tb, 0, stream>>>(
        xb, qkvT_l, nullptr, nullptr, nullptr, nullptr, qkv_a, 2048, 3072, 1024);
    // attention (512 balanced blocks)
    attn_kernel<<<dim3(512), tb, 0, stream>>>(qkv_a, attnb);
    // x = x + attn @ Wproj + bproj   (direct, fused residual+bias)
    gemm_bt<false, false, true, false, true, true, true, false><<<dim3(128), tb, 0, stream>>>(
        attnb, WprojT + (size_t)l * 1048576, bproj + l * 1024, xf, xf, nullptr, xb, 2048, 1024, 1024);
    // h = relu(x @ W1 + b1)
    gemm_bt<false, false, true, true, false, false, true, false><<<dim3(512), tb, 0, stream>>>(
        xb, W1T + (size_t)l * 4194304, b1 + l * 4096, nullptr, nullptr, nullptr, hb, 2048, 4096, 1024);
    // x = x + h @ W2 + b2   (split-K=4: 512 blocks; slices 2,3 in psum2)
    gemm_bt<false, true, false, false, false, true, false, false><<<dim3(512), tb, 0, stream>>>(
        hb, W2T + (size_t)l * 4194304, nullptr, nullptr, psum, psum2, nullptr, 2048, 1024, 4096);
    reduce_sk4<<<dim3(2048), tb, 0, stream>>>(psum, psum2, b2 + l * 1024, xf, xb, MN, 1024);
  }

  // ---- LM head: 128x256-tile GEMM, 512 threads, LDS-bounce epilogue
  gemm_lm<<<dim3(2000), dim3(512), 0, stream>>>(xb, WlmT, blm, out, 2048, 32000, 1024);
}

// Round 19
// 822.387 us; speedup vs baseline: 1.0182x; 1.0182x over previous
//
#include <hip/hip_runtime.h>
#include <stdint.h>

#define DEVI static __device__ __forceinline__

typedef __attribute__((ext_vector_type(8))) _Float16  f16x8;
typedef __attribute__((ext_vector_type(8))) uint16_t  u16x8;
typedef __attribute__((ext_vector_type(4))) uint16_t  u16x4;
typedef __attribute__((ext_vector_type(4))) float     f32x4;

DEVI uint16_t f2h(float f){ return __builtin_bit_cast(uint16_t, (_Float16)f); }

DEVI void gload_lds16(const void* g, void* l){
  __builtin_amdgcn_global_load_lds((__attribute__((address_space(1))) void*)g,
                                   (__attribute__((address_space(3))) void*)l, 16, 0, 0);
}
DEVI f16x8 frag_ld(const void* base, int byteoff){
  const u16x8* p = (const u16x8*)((const char*)base + byteoff);
  return __builtin_bit_cast(f16x8, *p);
}

// ---------------------------------------------------------------- prep_all
// ONE launch for all weight transposes + embedding (R16: -18us vs 8 launches).
__global__ __launch_bounds__(256) void prep_all(
    const float* __restrict__ Wq, const float* __restrict__ Wk,
    const float* __restrict__ Wv, const float* __restrict__ Wproj,
    const float* __restrict__ W1, const float* __restrict__ W2,
    const float* __restrict__ Wlm,
    const int* __restrict__ idx, const float* __restrict__ tok,
    const float* __restrict__ pos,
    uint16_t* __restrict__ qkvT, uint16_t* __restrict__ WprojT,
    uint16_t* __restrict__ W1T, uint16_t* __restrict__ W2T,
    uint16_t* __restrict__ WlmT, float* __restrict__ xf,
    uint16_t* __restrict__ xb)
{
  __shared__ float tile[64][65];
  const int id = blockIdx.x;
  const float* inp; uint16_t* outp;
  int ld_in, ld_out, r0, c0;

  if (id < 3072){                       // Wq/Wk/Wv: 3 x 1024 tiles
    const int which = id >> 10, t = id & 1023;
    const int x = t >> 6, z = t & 63;   // x: 16 row-tiles of D; z = l*16+h
    const float* W = (which == 0) ? Wq : (which == 1) ? Wk : Wv;
    inp  = W + (long long)z * 65536;
    outp = qkvT + (size_t)(z >> 4) * (3072 * 1024)
                + (size_t)(z & 15) * (64 * 1024)
                + (size_t)which * (1024 * 1024);
    ld_in = 64; ld_out = 1024; r0 = x * 64; c0 = 0;
  } else if (id < 4096){                // Wproj: 1024 tiles (x16,y16,z4)
    const int t = id - 3072;
    const int z = t & 3, y = (t >> 2) & 15, x = t >> 6;
    inp  = Wproj + (long long)z * 1048576;
    outp = WprojT + (size_t)z * 1048576;
    ld_in = 1024; ld_out = 1024; r0 = x * 64; c0 = y * 64;
  } else if (id < 8192){                // W1: 4096 tiles (x16,y64,z4)
    const int t = id - 4096;
    const int z = t & 3, y = (t >> 2) & 63, x = t >> 8;
    inp  = W1 + (long long)z * 4194304;
    outp = W1T + (size_t)z * 4194304;
    ld_in = 4096; ld_out = 1024; r0 = x * 64; c0 = y * 64;
  } else if (id < 12288){               // W2: 4096 tiles (x64,y16,z4)
    const int t = id - 8192;
    const int z = t & 3, y = (t >> 2) & 15, x = t >> 6;
    inp  = W2 + (long long)z * 4194304;
    outp = W2T + (size_t)z * 4194304;
    ld_in = 1024; ld_out = 4096; r0 = x * 64; c0 = y * 64;
  } else if (id < 20288){               // Wlm: 8000 tiles (x16,y500)
    const int t = id - 12288;
    const int x = t & 15, y = t >> 4;
    inp = Wlm; outp = WlmT;
    ld_in = 32000; ld_out = 1024; r0 = x * 64; c0 = y * 64;
  } else {                              // embed: 2048 blocks (b*T + t)
    const int t = id - 20288;
    const int d = threadIdx.x * 4;
    const int token = idx[t];
    const int tp = t & 1023;
    const float4 tv = *(const float4*)(tok + (size_t)token * 1024 + d);
    const float4 pv = *(const float4*)(pos + (size_t)tp * 1024 + d);
    float4 s; s.x = tv.x + pv.x; s.y = tv.y + pv.y; s.z = tv.z + pv.z; s.w = tv.w + pv.w;
    *(float4*)(xf + (size_t)t * 1024 + d) = s;
    uint16_t* o = xb + (size_t)t * 1024 + d;
    o[0] = f2h(s.x); o[1] = f2h(s.y); o[2] = f2h(s.z); o[3] = f2h(s.w);
    return;
  }

  // shared 64x64 transpose body (float4 reads, paired-row u32 writes)
  const int r16 = threadIdx.x >> 4, c4 = (threadIdx.x & 15) * 4;
  #pragma unroll
  for (int i = 0; i < 4; i++){
    int r = i * 16 + r16;
    const float4 v = *(const float4*)(inp + (long long)(r0 + r) * ld_in + (c0 + c4));
    tile[r][c4] = v.x; tile[r][c4 + 1] = v.y; tile[r][c4 + 2] = v.z; tile[r][c4 + 3] = v.w;
  }
  __syncthreads();
  const int rp = (threadIdx.x & 31) * 2;
  const int cy = threadIdx.x >> 5;
  #pragma unroll
  for (int i = 0; i < 8; i++){
    int c = i * 8 + cy;
    uint32_t v = (uint32_t)f2h(tile[rp][c]) | ((uint32_t)f2h(tile[rp + 1][c]) << 16);
    *(uint32_t*)(outp + (long long)(c0 + c) * ld_out + (r0 + rp)) = v;
  }
}

// ---------------------------------------------------------------- GEMM
// C(MxN) = A(MxK fp16, row-major) * Bt(NxK fp16)^T  [+bias] [+res] [relu]
// 128x128 tile, BK=64, 4 waves (2x2), mfma 16x16x32 f16, global_load_lds w16,
// XOR-swizzled LDS via pre-swizzled global source. XCD-chunked swizzle.
// launch_bounds(256,3): unified VGPR+AGPR = 132; occ-4 cap squeezed (R11).
// SK4: 4-way split-K (R17: -55us on FFN2; R19: applied to proj too —
// this family at <=1 block/CU runs at half pace).
// QSCALE folds D^-0.5 * log2(e) into Q so attn uses exp2 directly.
template<bool SPLITK, bool SK4, bool BIAS, bool RELU, bool RES, bool OUTF, bool OUTB, bool QSCALE>
__global__ __launch_bounds__(256, 3) void gemm_bt(
    const uint16_t* __restrict__ A, const uint16_t* __restrict__ Bt,
    const float* __restrict__ bias, const float* __restrict__ res,
    float* __restrict__ outf, float* __restrict__ outf2,
    uint16_t* __restrict__ outb,
    int M, int N, int K)
{
  __shared__ __align__(16) uint16_t As[128 * 64];
  __shared__ __align__(16) uint16_t Bs[128 * 64];
  const int tid = threadIdx.x, lane = tid & 63, wid = tid >> 6;

  const int Mt = M >> 7;
  int flat = blockIdx.x;
  int kidx = 0;
  if constexpr (SK4){ kidx = flat & 3; flat >>= 2; }
  else if constexpr (SPLITK){ kidx = flat & 1; flat >>= 1; }
  const int total = SK4 ? (gridDim.x >> 2) : (SPLITK ? (gridDim.x >> 1) : gridDim.x);
  const int wg = (flat & 7) * (total >> 3) + (flat >> 3);   // XCD-chunked, total%8==0
  const int bm = (wg % Mt) * 128, bn = (wg / Mt) * 128;
  int k0 = 0, k1 = K;
  if constexpr (SK4){ const int Kq = K >> 2; k0 = kidx * Kq; k1 = k0 + Kq; }
  else if constexpr (SPLITK){ const int Kh = K >> 1; k0 = kidx * Kh; k1 = k0 + Kh; }
  float* outp = outf;
  if constexpr (SK4) outp = ((kidx < 2) ? outf : outf2) + (size_t)(kidx & 1) * M * N;
  else if constexpr (SPLITK) outp = outf + (size_t)kidx * M * N;

  const uint16_t* gA[4]; const uint16_t* gB[4];
  #pragma unroll
  for (int i = 0; i < 4; i++){
    int c = i * 256 + tid;
    int row = c >> 3;
    int p = (c * 16) ^ ((row & 7) << 4);   // logical byte this LDS slot holds
    int off = (p >> 1) & 63;               // k-element within row
    gA[i] = A  + (size_t)(bm + row) * K + off;
    gB[i] = Bt + (size_t)(bn + row) * K + off;
  }

  f32x4 acc[4][4];
  const f32x4 fz = {0.f, 0.f, 0.f, 0.f};
  #pragma unroll
  for (int a = 0; a < 4; a++)
    #pragma unroll
    for (int n = 0; n < 4; n++) acc[a][n] = fz;

  const int lrow = lane & 15, lk2 = (lane >> 4) * 16;
  const int wr = (wid >> 1) * 64, wc = (wid & 1) * 64;

  for (int kt = k0; kt < k1; kt += 64){
    #pragma unroll
    for (int i = 0; i < 4; i++)
      gload_lds16(gA[i] + kt, (char*)As + (i * 256 + wid * 64) * 16);
    #pragma unroll
    for (int i = 0; i < 4; i++)
      gload_lds16(gB[i] + kt, (char*)Bs + (i * 256 + wid * 64) * 16);
    __syncthreads();
    #pragma unroll
    for (int kk = 0; kk < 2; kk++){
      f16x8 af[4], bfv[4];
      #pragma unroll
      for (int mf = 0; mf < 4; mf++){
        int row = wr + mf * 16 + lrow;
        af[mf] = frag_ld(As, (row * 128 + kk * 64 + lk2) ^ ((row & 7) << 4));
      }
      #pragma unroll
      for (int nf = 0; nf < 4; nf++){
        int row = wc + nf * 16 + lrow;
        bfv[nf] = frag_ld(Bs, (row * 128 + kk * 64 + lk2) ^ ((row & 7) << 4));
      }
      #pragma unroll
      for (int mf = 0; mf < 4; mf++)
        #pragma unroll
        for (int nf = 0; nf < 4; nf++)
          acc[mf][nf] = __builtin_amdgcn_mfma_f32_16x16x32_f16(af[mf], bfv[nf], acc[mf][nf], 0, 0, 0);
    }
    __syncthreads();
  }

  #pragma unroll
  for (int mf = 0; mf < 4; mf++){
    const int row0 = bm + wr + mf * 16 + (lane >> 4) * 4;
    #pragma unroll
    for (int nf = 0; nf < 4; nf++){
      const int col = bn + wc + nf * 16 + (lane & 15);
      float bv = 0.f;
      if constexpr (BIAS) bv = bias[col];
      float qs = 1.0f;
      if constexpr (QSCALE) qs = (col < 1024) ? 0.04508422f : 1.0f;  // log2(e)/32
      #pragma unroll
      for (int j = 0; j < 4; j++){
        float v = acc[mf][nf][j] + bv;
        size_t oi = (size_t)(row0 + j) * N + col;
        if constexpr (RES)  v += res[oi];
        if constexpr (RELU) v = fmaxf(v, 0.f);
        if constexpr (OUTF) outp[oi] = v;
        if constexpr (OUTB) outb[oi] = f2h(v * qs);
      }
    }
  }
}

// ------------------------------------------------------- LM-head GEMM
// 128x256 tile, BK=64, 512 threads / 8 waves (2Mx4N, each 64x64; acc 64
// VGPR). Proven single-buffer 2-barrier loop (R15/R18: structure-bound —
// occupancy doubling AND write-coalescing both neutral; do not touch).
__global__ __launch_bounds__(512, 1) void gemm_lm(
    const uint16_t* __restrict__ A, const uint16_t* __restrict__ Bt,
    const float* __restrict__ bias, float* __restrict__ outf,
    int M, int N, int K)
{
  __shared__ __align__(16) uint16_t As[128 * 64];
  __shared__ __align__(16) uint16_t Bs[256 * 64];
  const int tid = threadIdx.x, lane = tid & 63, wid = tid >> 6;

  const int Mt = M >> 7;                       // 16
  const int flat = blockIdx.x;
  const int wg = (flat & 7) * (gridDim.x >> 3) + (flat >> 3);
  const int bm = (wg % Mt) * 128, bn = (wg / Mt) * 256;

  const uint16_t* gA[2]; const uint16_t* gB[4];
  #pragma unroll
  for (int i = 0; i < 2; i++){
    int c = i * 512 + tid;
    int row = c >> 3;
    int p = (c * 16) ^ ((row & 7) << 4);
    int off = (p >> 1) & 63;
    gA[i] = A + (size_t)(bm + row) * K + off;
  }
  #pragma unroll
  for (int i = 0; i < 4; i++){
    int c = i * 512 + tid;
    int row = c >> 3;
    int p = (c * 16) ^ ((row & 7) << 4);
    int off = (p >> 1) & 63;
    gB[i] = Bt + (size_t)(bn + row) * K + off;
  }

  f32x4 acc[4][4];
  const f32x4 fz = {0.f, 0.f, 0.f, 0.f};
  #pragma unroll
  for (int a = 0; a < 4; a++)
    #pragma unroll
    for (int n = 0; n < 4; n++) acc[a][n] = fz;

  const int lrow = lane & 15, lk2 = (lane >> 4) * 16, g4 = (lane >> 4) * 4;
  const int wr = (wid >> 2) * 64, wc = (wid & 3) * 64;

  for (int kt = 0; kt < K; kt += 64){
    #pragma unroll
    for (int i = 0; i < 2; i++)
      gload_lds16(gA[i] + kt, (char*)As + (i * 512 + wid * 64) * 16);
    #pragma unroll
    for (int i = 0; i < 4; i++)
      gload_lds16(gB[i] + kt, (char*)Bs + (i * 512 + wid * 64) * 16);
    __syncthreads();
    #pragma unroll
    for (int kk = 0; kk < 2; kk++){
      f16x8 af[4], bfv[4];
      #pragma unroll
      for (int mf = 0; mf < 4; mf++){
        int row = wr + mf * 16 + lrow;
        af[mf] = frag_ld(As, (row * 128 + kk * 64 + lk2) ^ ((row & 7) << 4));
      }
      #pragma unroll
      for (int nf = 0; nf < 4; nf++){
        int row = wc + nf * 16 + lrow;
        bfv[nf] = frag_ld(Bs, (row * 128 + kk * 64 + lk2) ^ ((row & 7) << 4));
      }
      #pragma unroll
      for (int mf = 0; mf < 4; mf++)
        #pragma unroll
        for (int nf = 0; nf < 4; nf++)
          acc[mf][nf] = __builtin_amdgcn_mfma_f32_16x16x32_f16(af[mf], bfv[nf], acc[mf][nf], 0, 0, 0);
    }
    __syncthreads();
  }

  // epilogue: per-wave LDS-bounce transpose -> 256B coalesced stores
  float* lds_f = (float*)((char*)Bs + wid * 4096);   // wave-private 4KB
  const float bv = bias[bn + wc + lane];
  #pragma unroll
  for (int mf = 0; mf < 4; mf++){
    #pragma unroll
    for (int nf = 0; nf < 4; nf++)
      #pragma unroll
      for (int j = 0; j < 4; j++)
        lds_f[(g4 + j) * 64 + nf * 16 + lrow] = acc[mf][nf][j];
    #pragma unroll
    for (int r = 0; r < 16; r++){
      const float v = lds_f[r * 64 + lane] + bv;
      outf[(size_t)(bm + wr + mf * 16 + r) * N + (bn + wc + lane)] = v;
    }
  }
}

// 4-way split-K finish: xf += (p0+p1)+(p2+p3) + bias;  xb = fp16(xf)
__global__ __launch_bounds__(256) void reduce_sk4(
    const float* __restrict__ p, const float* __restrict__ p2,
    const float* __restrict__ bias,
    float* __restrict__ xf, uint16_t* __restrict__ xb, int MN, int N)
{
  const int i = (blockIdx.x * 256 + threadIdx.x) * 4;
  const float4 a0 = *(const float4*)(p + i);
  const float4 a1 = *(const float4*)(p + MN + i);
  const float4 a2 = *(const float4*)(p2 + i);
  const float4 a3 = *(const float4*)(p2 + MN + i);
  const int col = i & (N - 1);
  const float4 bv = *(const float4*)(bias + col);
  float4 x = *(float4*)(xf + i);
  x.x += (a0.x + a1.x) + (a2.x + a3.x) + bv.x;
  x.y += (a0.y + a1.y) + (a2.y + a3.y) + bv.y;
  x.z += (a0.z + a1.z) + (a2.z + a3.z) + bv.z;
  x.w += (a0.w + a1.w) + (a2.w + a3.w) + bv.w;
  *(float4*)(xf + i) = x;
  uint16_t* o = xb + i;
  o[0] = f2h(x.x); o[1] = f2h(x.y); o[2] = f2h(x.z); o[3] = f2h(x.w);
}

// ---------------------------------------------------------------- attention
// R9 base: launch_bounds(256,2), separate Qs, 56KB LDS, 512 balanced blocks.
// NO-MAX softmax; Q pre-scaled by D^-0.5*log2(e) in qkv epilogue so
// P = exp2(S) directly. Per-lane partial l, reduced once at end.
// 2 barriers/iter (Ps wave-private).
__global__ __launch_bounds__(256, 2) void attn_kernel(
    const uint16_t* __restrict__ qkv, uint16_t* __restrict__ out)
{
  const int bi = blockIdx.x;
  const int b  = bi >> 8;
  const int jj = bi & 255;
  const int h  = jj >> 4;
  int q64 = jj & 15;
  if (b) q64 = 15 - q64;

  __shared__ __align__(16) uint16_t Qs[64 * 64];
  __shared__ __align__(16) uint16_t Ks[128 * 64];
  __shared__ __align__(16) uint16_t Vt[64 * 128];   // V^T
  __shared__ __align__(16) uint16_t Ps[64 * 128];

  const int tid = threadIdx.x, lane = tid & 63, wid = tid >> 6;
  const size_t bt0 = (size_t)b * 1024;

  // staging map (16B granules, row-XOR-swizzle for 128B rows)
  int rowC[4], offC[4];
  #pragma unroll
  for (int i = 0; i < 4; i++){
    int c = i * 256 + tid;
    int row = c >> 3;
    int p = (c * 16) ^ ((row & 7) << 4);
    rowC[i] = row; offC[i] = (p >> 1) & 63;
  }

  // stage Q (rows q64*64 .. +64)
  #pragma unroll
  for (int i = 0; i < 2; i++)
    gload_lds16(qkv + (bt0 + q64 * 64 + rowC[i]) * 3072 + h * 64 + offC[i],
                (char*)Qs + (i * 256 + wid * 64) * 16);
  __syncthreads();

  const int lrow = lane & 15, lk2 = (lane >> 4) * 16, g4 = (lane >> 4) * 4;

  // hoist Q fragments to registers
  f16x8 aq[2];
  {
    int row = wid * 16 + lrow;
    #pragma unroll
    for (int kk = 0; kk < 2; kk++)
      aq[kk] = frag_ld(Qs, (row * 128 + kk * 64 + lk2) ^ ((row & 7) << 4));
  }

  float l_run[4];
  f32x4 acc_o[4];
  const f32x4 fz = {0.f, 0.f, 0.f, 0.f};
  #pragma unroll
  for (int j = 0; j < 4; j++){ l_run[j] = 0.f; acc_o[j] = fz; }

  const int tpV = (tid >> 3) * 2, d0V = (tid & 7) * 8;
  const int nkt = q64 >> 1;

  for (int kt = 0; kt <= nkt; ++kt){
    __syncthreads();   // prev iter LDS reads done before restage
    #pragma unroll
    for (int i = 0; i < 4; i++)
      gload_lds16(qkv + (bt0 + kt * 128 + rowC[i]) * 3072 + 1024 + h * 64 + offC[i],
                  (char*)Ks + (i * 256 + wid * 64) * 16);
    // V -> V^T: 2 iters, 2 rows x 8 cols per thread (u16x8 loads, u32 writes)
    #pragma unroll
    for (int i = 0; i < 2; i++){
      const int t = i * 64 + tpV;
      const uint16_t* src = qkv + (bt0 + kt * 128 + t) * 3072 + 2048 + h * 64 + d0V;
      const u16x8 v0 = *(const u16x8*)src;
      const u16x8 v1 = *(const u16x8*)(src + 3072);
      #pragma unroll
      for (int dd = 0; dd < 8; dd++){
        const int d = d0V + dd;
        const int byte = (d * 256 + t * 2) ^ ((((d >> 3) ^ d) & 15) << 4);
        *(uint32_t*)((char*)Vt + byte) = (uint32_t)v0[dd] | ((uint32_t)v1[dd] << 16);
      }
    }
    __syncthreads();

    // S = Q K^T  (rows wid*16..+16, 128 cols)
    f32x4 sf[8];
    #pragma unroll
    for (int n = 0; n < 8; n++) sf[n] = fz;
    __builtin_amdgcn_s_setprio(1);
    #pragma unroll
    for (int kk = 0; kk < 2; kk++){
      #pragma unroll
      for (int nf = 0; nf < 8; nf++){
        const int row = nf * 16 + lrow;
        const f16x8 bk = frag_ld(Ks, (row * 128 + kk * 64 + lk2) ^ ((row & 7) << 4));
        sf[nf] = __builtin_amdgcn_mfma_f32_16x16x32_f16(aq[kk], bk, sf[nf], 0, 0, 0);
      }
    }
    __builtin_amdgcn_s_setprio(0);

    // no-max softmax via exp2 (Q pre-scaled by log2e); masked = 0 (diag only)
    const bool diag = (kt == nkt);
    #pragma unroll
    for (int j = 0; j < 4; j++){
      float ps = 0.f;
      if (diag){
        const int rg = q64 * 64 + wid * 16 + g4 + j;
        #pragma unroll
        for (int nf = 0; nf < 8; nf++){
          const int cg = kt * 128 + nf * 16 + lrow;
          const float p = (cg <= rg) ? exp2f(sf[nf][j]) : 0.f;
          sf[nf][j] = p;
          ps += p;
        }
      } else {
        #pragma unroll
        for (int nf = 0; nf < 8; nf++){
          const float p = exp2f(sf[nf][j]);
          sf[nf][j] = p;
          ps += p;
        }
      }
      l_run[j] += ps;
      const int rl = wid * 16 + g4 + j;
      const int sw = (((rl >> 3) ^ rl) & 15) << 4;
      #pragma unroll
      for (int nf = 0; nf < 8; nf++){
        const int byte = (rl * 256 + (nf * 16 + lrow) * 2) ^ sw;
        *(uint16_t*)((char*)Ps + byte) = f2h(sf[nf][j]);
      }
    }
    // no barrier: Ps rows are wave-private (write+read same 16-row band)

    // O += P V
    __builtin_amdgcn_s_setprio(1);
    #pragma unroll
    for (int kk = 0; kk < 4; kk++){
      const int row = wid * 16 + lrow;
      const f16x8 pa = frag_ld(Ps, (row * 256 + kk * 64 + lk2) ^ ((((row >> 3) ^ row) & 15) << 4));
      #pragma unroll
      for (int nh = 0; nh < 4; nh++){
        const int n = nh * 16 + lrow;
        const f16x8 vb = frag_ld(Vt, (n * 256 + kk * 64 + lk2) ^ ((((n >> 3) ^ n) & 15) << 4));
        acc_o[nh] = __builtin_amdgcn_mfma_f32_16x16x32_f16(pa, vb, acc_o[nh], 0, 0, 0);
      }
    }
    __builtin_amdgcn_s_setprio(0);
  }

  // deferred 16-lane l reduction (once, not per tile)
  #pragma unroll
  for (int j = 0; j < 4; j++){
    #pragma unroll
    for (int mk = 1; mk < 16; mk <<= 1) l_run[j] += __shfl_xor(l_run[j], mk);
  }

  #pragma unroll
  for (int j = 0; j < 4; j++){
    const float inv = 1.f / l_run[j];
    const int rg = q64 * 64 + wid * 16 + g4 + j;
    #pragma unroll
    for (int nh = 0; nh < 4; nh++)
      out[(bt0 + rg) * 1024 + h * 64 + nh * 16 + lrow] = f2h(acc_o[nh][j] * inv);
  }
}

// ---------------------------------------------------------------- launch
extern "C" void kernel_launch(void* const* d_in, const int* in_sizes, int n_in,
                              void* d_out, int out_size, void* d_ws, size_t ws_size,
                              hipStream_t stream)
{
  const int*   idx   = (const int*)  d_in[0];
  const float* tok   = (const float*)d_in[1];
  const float* pos   = (const float*)d_in[2];
  const float* Wq    = (const float*)d_in[3];
  const float* Wk    = (const float*)d_in[4];
  const float* Wv    = (const float*)d_in[5];
  const float* Wproj = (const float*)d_in[6];
  const float* bproj = (const float*)d_in[7];
  const float* W1    = (const float*)d_in[8];
  const float* b1    = (const float*)d_in[9];
  const float* W2    = (const float*)d_in[10];
  const float* b2    = (const float*)d_in[11];
  const float* Wlm   = (const float*)d_in[12];
  const float* blm   = (const float*)d_in[13];
  float* out = (float*)d_out;

  char* ws = (char*)d_ws;
  size_t off = 0;
  auto alloc = [&](size_t bytes){ void* p = ws + off; off += (bytes + 255) & ~(size_t)255; return p; };
  uint16_t* qkvT   = (uint16_t*)alloc((size_t)4 * 3072 * 1024 * 2);
  uint16_t* WprojT = (uint16_t*)alloc((size_t)4 * 1024 * 1024 * 2);
  uint16_t* W1T    = (uint16_t*)alloc((size_t)4 * 4096 * 1024 * 2);
  uint16_t* W2T    = (uint16_t*)alloc((size_t)4 * 1024 * 4096 * 2);
  uint16_t* WlmT   = (uint16_t*)alloc((size_t)32000 * 1024 * 2);
  float*    xf     = (float*)   alloc((size_t)2048 * 1024 * 4);
  uint16_t* xb     = (uint16_t*)alloc((size_t)2048 * 1024 * 2);
  uint16_t* qkv_a  = (uint16_t*)alloc((size_t)2048 * 3072 * 2);
  uint16_t* attnb  = (uint16_t*)alloc((size_t)2048 * 1024 * 2);
  uint16_t* hb     = (uint16_t*)alloc((size_t)2048 * 4096 * 2);
  float*    psum   = (float*)   alloc((size_t)2 * 2048 * 1024 * 4);
  // FFN2 partials 2,3 alias dead qkv_a+attnb (16.78MB = 2 x MN x 4B).
  // proj partials 2,3 alias dead hb (16.78MB; FFN1 rewrites it AFTER the
  // proj reduce consumes it — same-stream ordering).
  float*    psum2  = (float*)qkv_a;
  float*    psumP  = (float*)hb;
  (void)ws_size; (void)in_sizes; (void)n_in; (void)out_size;

  const dim3 tb(256);
  const int MN = 2048 * 1024;

  // ---- ALL weight prep + embedding in ONE launch (22336 blocks)
  prep_all<<<dim3(22336), tb, 0, stream>>>(
      Wq, Wk, Wv, Wproj, W1, W2, Wlm, idx, tok, pos,
      qkvT, WprojT, W1T, W2T, WlmT, xf, xb);

  // ---- layers
  for (int l = 0; l < 4; ++l){
    const uint16_t* qkvT_l = qkvT + (size_t)l * 3072 * 1024;
    // qkv = x @ [Wq|Wk|Wv]  (fp16 out; Q pre-scaled by log2e/32)
    gemm_bt<false, false, false, false, false, false, true, true><<<dim3(384), tb, 0, stream>>>(
        xb, qkvT_l, nullptr, nullptr, nullptr, nullptr, qkv_a, 2048, 3072, 1024);
    // attention (512 balanced blocks)
    attn_kernel<<<dim3(512), tb, 0, stream>>>(qkv_a, attnb);
    // x = x + attn @ Wproj + bproj   (split-K=4: 512 blocks, 4 K-iters each;
    // partials 2,3 in psumP=hb; reduce fuses res+bias+dual-out)
    gemm_bt<false, true, false, false, false, true, false, false><<<dim3(512), tb, 0, stream>>>(
        attnb, WprojT + (size_t)l * 1048576, nullptr, nullptr, psum, psumP, nullptr, 2048, 1024, 1024);
    reduce_sk4<<<dim3(2048), tb, 0, stream>>>(psum, psumP, bproj + l * 1024, xf, xb, MN, 1024);
    // h = relu(x @ W1 + b1)
    gemm_bt<false, false, true, true, false, false, true, false><<<dim3(512), tb, 0, stream>>>(
        xb, W1T + (size_t)l * 4194304, b1 + l * 4096, nullptr, nullptr, nullptr, hb, 2048, 4096, 1024);
    // x = x + h @ W2 + b2   (split-K=4: slices 2,3 in psum2=qkv_a)
    gemm_bt<false, true, false, false, false, true, false, false><<<dim3(512), tb, 0, stream>>>(
        hb, W2T + (size_t)l * 4194304, nullptr, nullptr, psum, psum2, nullptr, 2048, 1024, 4096);
    reduce_sk4<<<dim3(2048), tb, 0, stream>>>(psum, psum2, b2 + l * 1024, xf, xb, MN, 1024);
  }

  // ---- LM head: 128x256-tile GEMM, 512 threads, LDS-bounce epilogue
  gemm_lm<<<dim3(2000), dim3(512), 0, stream>>>(xb, WlmT, blm, out, 2048, 32000, 1024);
}